// Round 5
// baseline (372.560 us; speedup 1.0000x reference)
//
#include <hip/hip_runtime.h>

// bf16 stored as raw ushort everywhere; MFMA consumes __bf16 vectors.
typedef unsigned short u16;
using bf16x8  = __attribute__((ext_vector_type(8))) __bf16;
using floatx4 = __attribute__((ext_vector_type(4))) float;

__device__ __forceinline__ u16 f2bf(float f) {
  unsigned int u = __builtin_bit_cast(unsigned int, f);
  u += 0x7fffu + ((u >> 16) & 1u);          // round-to-nearest-even
  return (u16)(u >> 16);
}
__device__ __forceinline__ float bf2f(u16 h) {
  unsigned int u = ((unsigned int)h) << 16;
  return __builtin_bit_cast(float, u);
}

#define AS1(p) ((const __attribute__((address_space(1))) void*)(p))
#define AS3(p) ((__attribute__((address_space(3))) void*)(p))

// ============ 256x256 8-wave phased engine (BK=32, 4-slot ring) ===========
// LDS ring: 4 slots x (A 16KB + B 16KB) = 128 KiB. Subtiled [16][16rows][32k]
// bf16 per operand-slot, st_16x32 XOR swizzle (byte ^= ((byte>>9)&1)<<5).
// Single barrier + counted per-wave vmcnt per K-tile (R4-verified):
// steady vmcnt(6) = A(T+2)x2 + B(T+2)x2 + A(T+3)x2 in flight.
#define NE_PROLOGUE(bmv, bnv)                                                \
  __shared__ u16 lds[65536];            /* 128 KiB */                        \
  const int tid = threadIdx.x;                                               \
  const int w = tid >> 6, lane = tid & 63;                                   \
  const int wm = (w >> 2) * 128, wn = (w & 3) * 64;                          \
  const int wm16 = (w >> 2) * 8;        /* A subtile base for this wave */   \
  const int wn4  = (w & 3) * 4;         /* B subtile base for this wave */   \
  const long bm = (bmv), bn = (bnv);                                         \
  floatx4 acc[8][4] = {};                                                    \
  const int fr = lane & 15;                                                  \
  const int kq = (lane >> 4) * 8;                                            \
  const int oc = (lane >> 4) * 4;                                            \
  /* staging: linear LDS dest (lane*16); source is inverse-swizzled */       \
  const int swz  = (lane * 16) ^ (((lane >> 5) & 1) << 5);                   \
  const int srow = swz >> 6;            /* [0,16) row within subtile */      \
  const int scol = (swz & 63) >> 1;     /* {0,8,16,24} k within tile */      \
  const int st0  = w * 2;               /* this wave's subtile pair */       \
  /* read-side swizzled byte offset within a subtile */                      \
  const int aoff = fr * 64 + ((kq * 2) ^ (((fr >> 3) & 1) << 5));

#define NE_SETUP_PTRS(Abp, Bbp, ldK)                                         \
  const u16* A0p = (Abp) + (long)(st0 * 16 + srow) * (ldK) + scol;           \
  const u16* A1p = A0p + 16L * (ldK);                                        \
  const u16* B0p = (Bbp) + (long)(st0 * 16 + srow) * (ldK) + scol;           \
  const u16* B1p = B0p + 16L * (ldK);

#define NE_SA(T)                                                             \
  { u16* d_ = lds + (((T) & 3) * 16384) + st0 * 512;                         \
    long o_ = (long)(T) * 32;                                                \
    __builtin_amdgcn_global_load_lds(AS1(A0p + o_), AS3(d_), 16, 0, 0);      \
    __builtin_amdgcn_global_load_lds(AS1(A1p + o_), AS3(d_ + 512), 16, 0, 0); }
#define NE_SB(T)                                                             \
  { u16* d_ = lds + (((T) & 3) * 16384) + 8192 + st0 * 512;                  \
    long o_ = (long)(T) * 32;                                                \
    __builtin_amdgcn_global_load_lds(AS1(B0p + o_), AS3(d_), 16, 0, 0);      \
    __builtin_amdgcn_global_load_lds(AS1(B1p + o_), AS3(d_ + 512), 16, 0, 0); }

#define NE_TILE_G(T, NT, MF)                                                 \
  {                                                                          \
    const char* sb_ = (const char*)lds + ((T) & 3) * 32768;                  \
    if ((T) + 2 < (NT)) NE_SB((T) + 2)                                       \
    if ((T) + 3 < (NT)) NE_SA((T) + 3)                                       \
    bf16x8 af[4], bf[4];                                                     \
    _Pragma("unroll")                                                        \
    for (int i = 0; i < 4; ++i)                                              \
      af[i] = *(const bf16x8*)(sb_ + (wm16 + i) * 1024 + aoff);              \
    _Pragma("unroll")                                                        \
    for (int i = 0; i < 4; ++i)                                              \
      bf[i] = *(const bf16x8*)(sb_ + 16384 + (wn4 + i) * 1024 + aoff);       \
    asm volatile("s_waitcnt lgkmcnt(0)" ::: "memory");                       \
    __builtin_amdgcn_sched_barrier(0);                                       \
    __builtin_amdgcn_s_setprio(1);                                           \
    _Pragma("unroll")                                                        \
    for (int mi = 0; mi < 4; ++mi)                                           \
      _Pragma("unroll")                                                      \
      for (int ni = 0; ni < 4; ++ni)                                         \
        acc[mi][ni] = MF(mi, ni, acc[mi][ni]);                               \
    __builtin_amdgcn_s_setprio(0);                                           \
    _Pragma("unroll")                                                        \
    for (int i = 0; i < 4; ++i)                                              \
      af[i] = *(const bf16x8*)(sb_ + (wm16 + 4 + i) * 1024 + aoff);          \
    asm volatile("s_waitcnt lgkmcnt(0)" ::: "memory");                       \
    __builtin_amdgcn_sched_barrier(0);                                       \
    __builtin_amdgcn_s_setprio(1);                                           \
    _Pragma("unroll")                                                        \
    for (int mi = 0; mi < 4; ++mi)                                           \
      _Pragma("unroll")                                                      \
      for (int ni = 0; ni < 4; ++ni)                                         \
        acc[4 + mi][ni] = MF(mi, ni, acc[4 + mi][ni]);                       \
    __builtin_amdgcn_s_setprio(0);                                           \
    if ((T) < (NT) - 3)       { asm volatile("s_waitcnt vmcnt(6)" ::: "memory"); } \
    else if ((T) == (NT) - 3) { asm volatile("s_waitcnt vmcnt(4)" ::: "memory"); } \
    else if ((T) == (NT) - 2) { asm volatile("s_waitcnt vmcnt(0)" ::: "memory"); } \
    __builtin_amdgcn_s_barrier();                                            \
    __builtin_amdgcn_sched_barrier(0);                                       \
  }

#define NE_MF_SWAP(mi, ni, c) __builtin_amdgcn_mfma_f32_16x16x32_bf16(bf[ni], af[mi], (c), 0, 0, 0)
#define NE_MF_NS(mi, ni, c)   __builtin_amdgcn_mfma_f32_16x16x32_bf16(af[mi], bf[ni], (c), 0, 0, 0)
#define NE_TILE(T, NT)    NE_TILE_G(T, NT, NE_MF_SWAP)
#define NE_TILE_NS(T, NT) NE_TILE_G(T, NT, NE_MF_NS)

#define NE_START()                                                           \
  NE_SA(0) NE_SB(0) NE_SA(1) NE_SB(1) NE_SA(2)                               \
  asm volatile("s_waitcnt vmcnt(6)" ::: "memory");                           \
  __builtin_amdgcn_s_barrier();                                              \
  __builtin_amdgcn_sched_barrier(0);

// ============ NE2: 128x256 variant (BK=32, 4-slot ring, 96 KiB) ===========
// Slot = A 8KB (8 subtiles) + B 16KB (16 subtiles) = 24KB; ring 4 = 96KB.
// 8 waves as 2M x 4N; per-wave output 64x64 (acc[4][4]).
// Stage per tile: A 1 load/thread (wave w -> A subtile w), B 2 loads/thread
// (subtiles 2w, 2w+1). Issue order per tile: SB(T+2) then SA(T+3) ->
// steady in-flight at wait = A(T+2) + B(T+2)x2 + A(T+3) = 4 loads.
// Tails: T==NT-3 -> 3, T==NT-2 -> 0. Prologue in-flight = 4.
#define NE2_PROLOGUE(bmv, bnv)                                               \
  __shared__ u16 lds[49152];            /* 96 KiB */                         \
  const int tid = threadIdx.x;                                               \
  const int w = tid >> 6, lane = tid & 63;                                   \
  const int wm = (w >> 2) * 64, wn = (w & 3) * 64;                           \
  const int wm4 = (w >> 2) * 4;         /* A subtile base for this wave */   \
  const int wn4 = (w & 3) * 4;          /* B subtile base for this wave */   \
  const long bm = (bmv), bn = (bnv);                                         \
  floatx4 acc[4][4] = {};                                                    \
  const int fr = lane & 15;                                                  \
  const int kq = (lane >> 4) * 8;                                            \
  const int oc = (lane >> 4) * 4;                                            \
  const int swz  = (lane * 16) ^ (((lane >> 5) & 1) << 5);                   \
  const int srow = swz >> 6;                                                 \
  const int scol = (swz & 63) >> 1;                                          \
  const int st0  = w * 2;                                                    \
  const int aoff = fr * 64 + ((kq * 2) ^ (((fr >> 3) & 1) << 5));

#define NE2_SETUP_PTRS(Abp, Bbp, ldK)                                        \
  const u16* A0p = (Abp) + (long)(w * 16 + srow) * (ldK) + scol;             \
  const u16* B0p = (Bbp) + (long)(st0 * 16 + srow) * (ldK) + scol;           \
  const u16* B1p = B0p + 16L * (ldK);

#define NE2_SA(T)                                                            \
  { u16* d_ = lds + (((T) & 3) * 12288) + w * 512;                           \
    __builtin_amdgcn_global_load_lds(AS1(A0p + (long)(T) * 32), AS3(d_), 16, 0, 0); }
#define NE2_SB(T)                                                            \
  { u16* d_ = lds + (((T) & 3) * 12288) + 4096 + st0 * 512;                  \
    long o_ = (long)(T) * 32;                                                \
    __builtin_amdgcn_global_load_lds(AS1(B0p + o_), AS3(d_), 16, 0, 0);      \
    __builtin_amdgcn_global_load_lds(AS1(B1p + o_), AS3(d_ + 512), 16, 0, 0); }

#define NE2_TILE_G(T, NT, MF)                                                \
  {                                                                          \
    const char* sb_ = (const char*)lds + ((T) & 3) * 24576;                  \
    if ((T) + 2 < (NT)) NE2_SB((T) + 2)                                      \
    if ((T) + 3 < (NT)) NE2_SA((T) + 3)                                      \
    bf16x8 af[4], bf[4];                                                     \
    _Pragma("unroll")                                                        \
    for (int i = 0; i < 4; ++i)                                              \
      af[i] = *(const bf16x8*)(sb_ + (wm4 + i) * 1024 + aoff);               \
    _Pragma("unroll")                                                        \
    for (int i = 0; i < 4; ++i)                                              \
      bf[i] = *(const bf16x8*)(sb_ + 8192 + (wn4 + i) * 1024 + aoff);        \
    asm volatile("s_waitcnt lgkmcnt(0)" ::: "memory");                       \
    __builtin_amdgcn_sched_barrier(0);                                       \
    __builtin_amdgcn_s_setprio(1);                                           \
    _Pragma("unroll")                                                        \
    for (int mi = 0; mi < 4; ++mi)                                           \
      _Pragma("unroll")                                                      \
      for (int ni = 0; ni < 4; ++ni)                                         \
        acc[mi][ni] = MF(mi, ni, acc[mi][ni]);                               \
    __builtin_amdgcn_s_setprio(0);                                           \
    if ((T) < (NT) - 3)       { asm volatile("s_waitcnt vmcnt(4)" ::: "memory"); } \
    else if ((T) == (NT) - 3) { asm volatile("s_waitcnt vmcnt(3)" ::: "memory"); } \
    else if ((T) == (NT) - 2) { asm volatile("s_waitcnt vmcnt(0)" ::: "memory"); } \
    __builtin_amdgcn_s_barrier();                                            \
    __builtin_amdgcn_sched_barrier(0);                                       \
  }

#define NE2_TILE(T, NT)    NE2_TILE_G(T, NT, NE_MF_SWAP)
#define NE2_TILE_NS(T, NT) NE2_TILE_G(T, NT, NE_MF_NS)

#define NE2_START()                                                          \
  NE2_SA(0) NE2_SB(0) NE2_SA(1) NE2_SB(1) NE2_SA(2)                          \
  asm volatile("s_waitcnt vmcnt(4)" ::: "memory");                           \
  __builtin_amdgcn_s_barrier();                                              \
  __builtin_amdgcn_sched_barrier(0);

// Batch-combined QK^T + unnormalized exp — phased 256^2 engine.
// Grid (8,64) = 512 blocks x 512 thr = 2.0 rounds/CU.
__global__ __launch_bounds__(512, 2) void gemm_qk_exp(
    const u16* __restrict__ q, const u16* __restrict__ k,
    u16* __restrict__ probs, float* __restrict__ lpartT, float alpha)
{
  const int N = 4096;
  const int xcd = blockIdx.x;
  const int j = blockIdx.y;
  const long b = xcd >> 2;
  const int by = (xcd & 3) * 4 + (j & 3);   // [0,16)
  const int bx = j >> 2;                    // [0,16)

  NE_PROLOGUE((long)by * 256, (long)bx * 256);
  const u16* Ab = q + b * 4096 * 1024 + bm * 1024;
  const u16* Bb = k + b * 4096 * 1024 + bn * 1024;
  NE_SETUP_PTRS(Ab, Bb, 1024);
  u16* P = probs + b * 4096L * 4096;
  float* lp = lpartT + b * 4096 * 64;

  NE_START()
  for (int T = 0; T < 32; ++T) NE_TILE(T, 32)

  const float a2 = alpha * 1.44269504f;     // exp(x*alpha) = exp2(x*a2)
  const int cg = bx * 4 + (w & 3);          // 64-col group index
#pragma unroll
  for (int mi = 0; mi < 8; ++mi) {
    long row = bm + wm + mi * 16 + fr;
    float rs = 0.f;
#pragma unroll
    for (int ni = 0; ni < 4; ++ni) {
      long colb = bn + wn + ni * 16 + oc;
      float e0 = __builtin_amdgcn_exp2f(acc[mi][ni][0] * a2);
      float e1 = __builtin_amdgcn_exp2f(acc[mi][ni][1] * a2);
      float e2 = __builtin_amdgcn_exp2f(acc[mi][ni][2] * a2);
      float e3 = __builtin_amdgcn_exp2f(acc[mi][ni][3] * a2);
      rs += (e0 + e1) + (e2 + e3);
      ushort4 o;
      o.x = f2bf(e0); o.y = f2bf(e1); o.z = f2bf(e2); o.w = f2bf(e3);
      *(ushort4*)(P + row * N + colb) = o;
    }
    rs += __shfl_xor(rs, 16);
    rs += __shfl_xor(rs, 32);
    if (lane < 16)
      lp[(bm + wm + mi * 16 + lane) * 64 + cg] = rs;
  }
}

// Batch-combined PV, split-K=2 — phased 256^2 engine.
// Grid (8,32) = 256 blocks x 512 thr = exactly 1 block/CU, one full round.
__global__ __launch_bounds__(512, 2) void gemm_pv_splitk2(
    const u16* __restrict__ probs, const u16* __restrict__ vT,
    u16* __restrict__ pA, u16* __restrict__ pB)
{
  const int xcd = blockIdx.x;
  const int j = blockIdx.y;
  const long b = xcd >> 2;
  const int sp = (xcd >> 1) & 1;
  const int by = (xcd & 1) * 8 + (j & 7);   // [0,16)
  const int bx = j >> 3;                    // [0,4)

  NE_PROLOGUE((long)by * 256, (long)bx * 256);
  const u16* Ab = probs + b * 4096L * 4096 + bm * 4096 + sp * 2048;
  const u16* Bb = vT + b * 1024L * 4096 + bn * 4096 + sp * 2048;
  NE_SETUP_PTRS(Ab, Bb, 4096);
  u16* part = (b ? pB : pA) + (long)sp * 4096 * 1024;

  NE_START()
  for (int T = 0; T < 64; ++T) NE_TILE(T, 64)

#pragma unroll
  for (int mi = 0; mi < 8; ++mi) {
    long row = bm + wm + mi * 16 + fr;
#pragma unroll
    for (int ni = 0; ni < 4; ++ni) {
      long colb = bn + wn + ni * 16 + oc;
      ushort4 o;
      o.x = f2bf(acc[mi][ni][0]);
      o.y = f2bf(acc[mi][ni][1]);
      o.z = f2bf(acc[mi][ni][2]);
      o.w = f2bf(acc[mi][ni][3]);
      *(ushort4*)(part + row * 1024 + colb) = o;
    }
  }
}

// Fused QKV projection — NE2 128x256 engine. A=xb [8192,1024],
// Bt=WqkvT [3072,1024]. Grid (8,96) = 768 blocks = 3.0 integral rounds/CU.
// xcd owns A-rows [xcd*1024,+1024) (2MB, L2-resident), sweeps 12 n-tiles.
// Block-uniform: bx<8 -> q/k (swapped epi); bx>=8 -> v (NS epi into vT).
__global__ __launch_bounds__(512, 2) void gemm_qkv(
    const u16* __restrict__ A, const u16* __restrict__ Bt,
    u16* __restrict__ qb, u16* __restrict__ kb, u16* __restrict__ vT,
    const float* __restrict__ bq, const float* __restrict__ bk,
    const float* __restrict__ bv)
{
  const int xcd = blockIdx.x;
  const int j = blockIdx.y;                 // [0,96)
  const int by = xcd * 8 + (j & 7);         // [0,64)
  const int bx = j >> 3;                    // [0,12)

  NE2_PROLOGUE((long)by * 128, (long)bx * 256);
  const u16* Ab = A + bm * 1024;
  const u16* Bb = Bt + bn * 1024;
  NE2_SETUP_PTRS(Ab, Bb, 1024);

  if (bn < 2048) {
    NE2_START()
    for (int T = 0; T < 32; ++T) NE2_TILE(T, 32)
    u16* C = (bn < 1024) ? qb : kb;
    const float* bias = (bn < 1024) ? bq : bk;
#pragma unroll
    for (int mi = 0; mi < 4; ++mi) {
      long row = bm + wm + mi * 16 + fr;
#pragma unroll
      for (int ni = 0; ni < 4; ++ni) {
        long colg = bn + wn + ni * 16 + oc;
        long cc = colg & 1023;
        float4 bv4 = *(const float4*)(bias + cc);
        ushort4 o;
        o.x = f2bf(acc[mi][ni][0] + bv4.x);
        o.y = f2bf(acc[mi][ni][1] + bv4.y);
        o.z = f2bf(acc[mi][ni][2] + bv4.z);
        o.w = f2bf(acc[mi][ni][3] + bv4.w);
        *(ushort4*)(C + row * 1024 + cc) = o;
      }
    }
  } else {
    NE2_START()
    for (int T = 0; T < 32; ++T) NE2_TILE_NS(T, 32)
    const int orow = (lane >> 4) * 4;       // NS: 4 consecutive rows
    const long b_ = bm >> 12;               // block entirely in one batch
    const long s0 = (bm & 4095) + wm;
    u16* vb = vT + b_ * (1024L * 4096);
#pragma unroll
    for (int ni = 0; ni < 4; ++ni) {
      long d = bn + wn + ni * 16 + fr - 2048;
      float bvv = bv[d];
#pragma unroll
      for (int mi = 0; mi < 4; ++mi) {
        long s = s0 + mi * 16 + orow;
        ushort4 o;
        o.x = f2bf(acc[mi][ni][0] + bvv);
        o.y = f2bf(acc[mi][ni][1] + bvv);
        o.z = f2bf(acc[mi][ni][2] + bvv);
        o.w = f2bf(acc[mi][ni][3] + bvv);
        *(ushort4*)(vb + d * 4096L + s) = o;
      }
    }
  }
}

// Final projection — NE2 128x256 engine. C = ob*WoT^T + bias, fp32 out.
// Grid (8,32) = 256 blocks = 1.0 round/CU.
__global__ __launch_bounds__(512, 2) void gemm_bt(
    const u16* __restrict__ A, const u16* __restrict__ Bt,
    float* __restrict__ Cout, const float* __restrict__ bias)
{
  const int xcd = blockIdx.x;
  const int j = blockIdx.y;                 // [0,32)
  const int by = xcd * 8 + (j & 7);         // [0,64)
  const int bx = j >> 3;                    // [0,4)

  NE2_PROLOGUE((long)by * 128, (long)bx * 256);
  const u16* Ab = A + bm * 1024;
  const u16* Bb = Bt + bn * 1024;
  NE2_SETUP_PTRS(Ab, Bb, 1024);

  NE2_START()
  for (int T = 0; T < 32; ++T) NE2_TILE(T, 32)

#pragma unroll
  for (int mi = 0; mi < 4; ++mi) {
    long row = bm + wm + mi * 16 + fr;
#pragma unroll
    for (int ni = 0; ni < 4; ++ni) {
      long colb = bn + wn + ni * 16 + oc;
      float4 bv4 = *(const float4*)(bias + colb);
      float4 o;
      o.x = acc[mi][ni][0] + bv4.x;
      o.y = acc[mi][ni][1] + bv4.y;
      o.z = acc[mi][ni][2] + bv4.z;
      o.w = acc[mi][ni][3] + bv4.w;
      *(float4*)(Cout + row * 1024 + colb) = o;
    }
  }
}

// Combined reduce + softmax-normalize: grid (4096 rows, 2 batches).
__global__ __launch_bounds__(256) void reduce2_div_row(
    const u16* __restrict__ pA, const u16* __restrict__ pB,
    const float* __restrict__ lpartT, u16* __restrict__ ob)
{
  const int row = blockIdx.x;           // [0,4096)
  const long b = blockIdx.y;
  const int tid = threadIdx.x;
  const u16* part = b ? pB : pA;
  const float* lp = lpartT + b * 4096 * 64;
  __shared__ float sl;
  if (tid < 64) {
    float s = lp[(long)row * 64 + tid];
#pragma unroll
    for (int off = 32; off; off >>= 1) s += __shfl_down(s, off);
    if (tid == 0) sl = s;
  }
  __syncthreads();
  const float inv = 1.0f / sl;
  const long base = (long)row * 1024 + tid * 4;
  float acc4[4] = {0.f, 0.f, 0.f, 0.f};
#pragma unroll
  for (int s = 0; s < 2; ++s) {
    ushort4 p = *(const ushort4*)(part + (long)s * 4096 * 1024 + base);
    acc4[0] += bf2f(p.x); acc4[1] += bf2f(p.y);
    acc4[2] += bf2f(p.z); acc4[3] += bf2f(p.w);
  }
  ushort4 o;
  o.x = f2bf(acc4[0] * inv);
  o.y = f2bf(acc4[1] * inv);
  o.z = f2bf(acc4[2] * inv);
  o.w = f2bf(acc4[3] * inv);
  *(ushort4*)(ob + b * 4096L * 1024 + base) = o;
}

// Fused prep: blocks [0,8192) cast x (fp32->bf16, float4); blocks
// [8192,12288) transpose+cast the 4 weight matrices (z = (blk-8192)>>10).
__global__ __launch_bounds__(256) void prep(
    const float* __restrict__ x, u16* __restrict__ xb,
    const float* __restrict__ W0, const float* __restrict__ W1,
    const float* __restrict__ W2, const float* __restrict__ W3,
    u16* __restrict__ O0, u16* __restrict__ O1,
    u16* __restrict__ O2, u16* __restrict__ O3)
{
  __shared__ float tile[32][33];
  int blk = blockIdx.x;
  if (blk < 8192) {
    int i = blk * 256 + threadIdx.x;      // 2M float4s
    float4 f = ((const float4*)x)[i];
    ushort4 o;
    o.x = f2bf(f.x); o.y = f2bf(f.y); o.z = f2bf(f.z); o.w = f2bf(f.w);
    ((ushort4*)xb)[i] = o;
  } else {
    blk -= 8192;
    const int z = blk >> 10, t = blk & 1023;
    const float* in = (z == 0) ? W0 : (z == 1) ? W1 : (z == 2) ? W2 : W3;
    u16* outp = (z == 0) ? O0 : (z == 1) ? O1 : (z == 2) ? O2 : O3;
    const int bx = (t & 31) * 32, by = (t >> 5) * 32;
    const int tx = threadIdx.x & 31, ty = threadIdx.x >> 5;   // 32 x 8
    for (int i = ty; i < 32; i += 8)
      tile[i][tx] = in[(long)(by + i) * 1024 + bx + tx];
    __syncthreads();
    for (int i = ty; i < 32; i += 8)
      outp[(long)(bx + i) * 1024 + by + tx] = f2bf(tile[tx][i]);
  }
}

extern "C" void kernel_launch(void* const* d_in, const int* in_sizes, int n_in,
                              void* d_out, int out_size, void* d_ws, size_t ws_size,
                              hipStream_t stream) {
  const float* x  = (const float*)d_in[0];
  const float* Wq = (const float*)d_in[1];
  const float* bq = (const float*)d_in[2];
  const float* Wk = (const float*)d_in[3];
  const float* bk = (const float*)d_in[4];
  const float* Wv = (const float*)d_in[5];
  const float* bv = (const float*)d_in[6];
  const float* Wo = (const float*)d_in[7];
  const float* bo = (const float*)d_in[8];
  float* out = (float*)d_out;

  const int B = 2, S = 4096, D = 1024;
  const long MB = 1L << 20;

  // ---- workspace layout (top usage 152 MiB; ws_size >= 168 MiB proven) ----
  //  [0,16M)    qb  bf16 [8192,1024]   -- dead after QK_exp; reused as
  //                                       PV bf16 partials batch0 [2][4096][1024]
  //  [16,32M)   kb  bf16 [8192,1024]
  //  [32,48M)   vT  bf16 [B][1024][4096]
  //  [48,64M)   xb  bf16 [8192,1024]   -- aliased with ob (xb dead before PV)
  //  [64,72M)   WqkvT bf16 [3072,1024] + WoT bf16 [1024,1024]
  //  [72,136M)  probs bf16 [B][4096][4096]  (both batches)
  //  [136,152M) PV bf16 partials batch1 [2][4096][1024]
  // d_out (32MB fp32, dead until final proj) hosts lpartT [B][4096][64] fp32.
  char* w = (char*)d_ws;
  u16* qb  = (u16*)(w);
  u16* kb  = (u16*)(w + 16 * MB);
  u16* vT  = (u16*)(w + 32 * MB);
  u16* xb  = (u16*)(w + 48 * MB);
  u16* ob  = xb;                        // alias: xb dead before ob written
  u16* WqkvT = (u16*)(w + 64 * MB);
  u16* WoT = WqkvT + 3072L * 1024;
  u16* probs = (u16*)(w + 72 * MB);
  u16* partA = (u16*)(w);               // over qb, dead after QK_exp
  u16* partB = (u16*)(w + 136 * MB);
  float* lpartT = (float*)d_out;        // [2][4096][64] fp32 = 2MB

  // 1. fused prep: cast x + transpose/cast all 4 weights
  prep<<<dim3(8192 + 4096), 256, 0, stream>>>(
      x, xb, Wq, Wk, Wv, Wo,
      WqkvT, WqkvT + 1024L * 1024, WqkvT + 2048L * 1024, WoT);

  // 2. fused QKV projection: grid (8,96) = 768 blocks = 3.0 rounds (NE2)
  gemm_qkv<<<dim3(8, 96), 512, 0, stream>>>(
      xb, WqkvT, qb, kb, vT, bq, bk, bv);

  // 3. attention, both batches per launch (phased 256^2 engine)
  const float scale = 0.125f;  // 1/sqrt(64)
  gemm_qk_exp<<<dim3(8, 64), 512, 0, stream>>>(
      qb, kb, probs, lpartT, scale);
  // qb now dead -> partA overlays it
  gemm_pv_splitk2<<<dim3(8, 32), 512, 0, stream>>>(
      probs, vT, partA, partB);
  reduce2_div_row<<<dim3(S, B), 256, 0, stream>>>(partA, partB, lpartT, ob);

  // 4. final projection -> fp32 d_out (NE2, 256 blocks = 1.0 round)
  gemm_bt<<<dim3(8, 32), 512, 0, stream>>>(ob, WoT, out, bo);
}

// Round 6
// 363.190 us; speedup vs baseline: 1.0258x; 1.0258x over previous
//
#include <hip/hip_runtime.h>

// bf16 stored as raw ushort everywhere; MFMA consumes __bf16 vectors.
typedef unsigned short u16;
using bf16x8  = __attribute__((ext_vector_type(8))) __bf16;
using floatx4 = __attribute__((ext_vector_type(4))) float;

__device__ __forceinline__ u16 f2bf(float f) {
  unsigned int u = __builtin_bit_cast(unsigned int, f);
  u += 0x7fffu + ((u >> 16) & 1u);          // round-to-nearest-even
  return (u16)(u >> 16);
}
__device__ __forceinline__ float bf2f(u16 h) {
  unsigned int u = ((unsigned int)h) << 16;
  return __builtin_bit_cast(float, u);
}

#define AS1(p) ((const __attribute__((address_space(1))) void*)(p))
#define AS3(p) ((__attribute__((address_space(3))) void*)(p))

// ======= NE2R3: 128x256 phased engine, BK=32, RING-3 (72 KiB), 2 blk/CU ====
// R5 post-mortem: 1-blk/CU barrier-synced blocks ALTERNATE LDS and MFMA
// phases (per-tile: reads ~1150cy then MFMA ~1030cy, pipes never overlap ->
// MfmaUtil 31%). Fix = second independent block per CU (m114 overlap):
// ring-3 x 24KB slots = 72KB LDS -> 2 blocks/CU at launch_bounds(512,4).
// Slot = A 8KB (8 subtiles of [16rows][32k]) + B 16KB (16 subtiles).
// st_16x32 XOR swizzle both-sides (linear gload_lds dest + inverse-swizzled
// global src + swizzled read) — bank-conflict-free (R3-verified, PMC=0).
// Counted vmcnt, ring-3: tile T stages {B,A}(T+2) (3 loads/thread) into slot
// (T+2)%3; steady outstanding at wait = 3 -> vmcnt(3); tails: T==NT-2 -> 0.
// Safety: slot (T+2)%3 last read at T-1; those reads precede every wave's
// end-of-(T-1) barrier arrival, and stages issue after that barrier.
#define NE2_PROLOGUE(bmv, bnv)                                               \
  __shared__ u16 lds[36864];            /* 72 KiB = 3 x 24KB */              \
  const int tid = threadIdx.x;                                               \
  const int w = tid >> 6, lane = tid & 63;                                   \
  const int wm = (w >> 2) * 64, wn = (w & 3) * 64;                           \
  const int wm4 = (w >> 2) * 4;         /* A subtile base for this wave */   \
  const int wn4 = (w & 3) * 4;          /* B subtile base for this wave */   \
  const long bm = (bmv), bn = (bnv);                                         \
  floatx4 acc[4][4] = {};                                                    \
  const int fr = lane & 15;                                                  \
  const int kq = (lane >> 4) * 8;                                            \
  const int oc = (lane >> 4) * 4;                                            \
  const int swz  = (lane * 16) ^ (((lane >> 5) & 1) << 5);                   \
  const int srow = swz >> 6;                                                 \
  const int scol = (swz & 63) >> 1;                                          \
  const int st0  = w * 2;                                                    \
  const int aoff = fr * 64 + ((kq * 2) ^ (((fr >> 3) & 1) << 5));

#define NE2_SETUP_PTRS(Abp, Bbp, ldK)                                        \
  const u16* A0p = (Abp) + (long)(w * 16 + srow) * (ldK) + scol;             \
  const u16* B0p = (Bbp) + (long)(st0 * 16 + srow) * (ldK) + scol;           \
  const u16* B1p = B0p + 16L * (ldK);

// Stage tile TT into ring slot S (slot stride 12288 u16 = 24 KB).
#define NE2_SA(TT, S)                                                        \
  { u16* d_ = lds + (S) * 12288 + w * 512;                                   \
    __builtin_amdgcn_global_load_lds(AS1(A0p + (long)(TT) * 32), AS3(d_), 16, 0, 0); }
#define NE2_SB(TT, S)                                                        \
  { u16* d_ = lds + (S) * 12288 + 4096 + st0 * 512;                          \
    long o_ = (long)(TT) * 32;                                               \
    __builtin_amdgcn_global_load_lds(AS1(B0p + o_), AS3(d_), 16, 0, 0);      \
    __builtin_amdgcn_global_load_lds(AS1(B1p + o_), AS3(d_ + 512), 16, 0, 0); }

#define NE_MF_SWAP(mi, ni, c) __builtin_amdgcn_mfma_f32_16x16x32_bf16(bf[ni], af[mi], (c), 0, 0, 0)
#define NE_MF_NS(mi, ni, c)   __builtin_amdgcn_mfma_f32_16x16x32_bf16(af[mi], bf[ni], (c), 0, 0, 0)

// One K-tile: stage (T+2)->slot sW, read slot sR, lgkm, 16 MFMA, counted
// vmcnt, single barrier. sR/sW maintained by the caller (mod-3 rotation).
#define NE2_TILE_G(T, NT, sR, sW, MF)                                        \
  {                                                                          \
    const char* sb_ = (const char*)lds + (sR) * 24576;                       \
    if ((T) + 2 < (NT)) { NE2_SB((T) + 2, sW) NE2_SA((T) + 2, sW) }          \
    bf16x8 af[4], bf[4];                                                     \
    _Pragma("unroll")                                                        \
    for (int i = 0; i < 4; ++i)                                              \
      af[i] = *(const bf16x8*)(sb_ + (wm4 + i) * 1024 + aoff);               \
    _Pragma("unroll")                                                        \
    for (int i = 0; i < 4; ++i)                                              \
      bf[i] = *(const bf16x8*)(sb_ + 8192 + (wn4 + i) * 1024 + aoff);        \
    asm volatile("s_waitcnt lgkmcnt(0)" ::: "memory");                       \
    __builtin_amdgcn_sched_barrier(0);                                       \
    __builtin_amdgcn_s_setprio(1);                                           \
    _Pragma("unroll")                                                        \
    for (int mi = 0; mi < 4; ++mi)                                           \
      _Pragma("unroll")                                                      \
      for (int ni = 0; ni < 4; ++ni)                                         \
        acc[mi][ni] = MF(mi, ni, acc[mi][ni]);                               \
    __builtin_amdgcn_s_setprio(0);                                           \
    if ((T) < (NT) - 2)       { asm volatile("s_waitcnt vmcnt(3)" ::: "memory"); } \
    else if ((T) == (NT) - 2) { asm volatile("s_waitcnt vmcnt(0)" ::: "memory"); } \
    __builtin_amdgcn_s_barrier();                                            \
    __builtin_amdgcn_sched_barrier(0);                                       \
  }

// Prologue: stage slots 0,1 (6 loads); slot 0 ready when newest 3 remain.
#define NE2_START()                                                          \
  NE2_SA(0, 0) NE2_SB(0, 0) NE2_SA(1, 1) NE2_SB(1, 1)                        \
  asm volatile("s_waitcnt vmcnt(3)" ::: "memory");                           \
  __builtin_amdgcn_s_barrier();                                              \
  __builtin_amdgcn_sched_barrier(0);

#define NE2_LOOP(NT, TILE_MACRO)                                             \
  {                                                                          \
    int sR = 0, sW = 2;                                                      \
    for (int T = 0; T < (NT); ++T) {                                         \
      TILE_MACRO(T, (NT), sR, sW)                                            \
      sR = (sR == 2) ? 0 : sR + 1;                                           \
      sW = (sW == 2) ? 0 : sW + 1;                                           \
    }                                                                        \
  }

#define NE2_TILE(T, NT, sR, sW)    NE2_TILE_G(T, NT, sR, sW, NE_MF_SWAP)
#define NE2_TILE_NS(T, NT, sR, sW) NE2_TILE_G(T, NT, sR, sW, NE_MF_NS)

// Batch-combined QK^T + unnormalized exp — NE2R3.
// Grid (8,128) = 1024 blocks = 2 rounds of 2/CU. xcd owns batch xcd>>2 and
// an 8-m-tile band; sweeps 16 n-tiles. P = exp(scale*q k^T) bf16;
// lpartT[b][row][64] fp32 (64-col-group partial rowsums).
__global__ __launch_bounds__(512, 4) void gemm_qk_exp(
    const u16* __restrict__ q, const u16* __restrict__ k,
    u16* __restrict__ probs, float* __restrict__ lpartT, float alpha)
{
  const int N = 4096;
  const int xcd = blockIdx.x;
  const int j = blockIdx.y;                 // [0,128)
  const long b = xcd >> 2;
  const int by = (xcd & 3) * 8 + (j & 7);   // [0,32)
  const int bx = j >> 3;                    // [0,16)

  NE2_PROLOGUE((long)by * 128, (long)bx * 256);
  const u16* Ab = q + b * 4096 * 1024 + bm * 1024;
  const u16* Bb = k + b * 4096 * 1024 + bn * 1024;
  NE2_SETUP_PTRS(Ab, Bb, 1024);
  u16* P = probs + b * 4096L * 4096;
  float* lp = lpartT + b * 4096 * 64;

  NE2_START()
  NE2_LOOP(32, NE2_TILE)

  const float a2 = alpha * 1.44269504f;     // exp(x*alpha) = exp2(x*a2)
  const int cg = bx * 4 + (w & 3);          // 64-col group index
#pragma unroll
  for (int mi = 0; mi < 4; ++mi) {
    long row = bm + wm + mi * 16 + fr;
    float rs = 0.f;
#pragma unroll
    for (int ni = 0; ni < 4; ++ni) {
      long colb = bn + wn + ni * 16 + oc;
      float e0 = __builtin_amdgcn_exp2f(acc[mi][ni][0] * a2);
      float e1 = __builtin_amdgcn_exp2f(acc[mi][ni][1] * a2);
      float e2 = __builtin_amdgcn_exp2f(acc[mi][ni][2] * a2);
      float e3 = __builtin_amdgcn_exp2f(acc[mi][ni][3] * a2);
      rs += (e0 + e1) + (e2 + e3);
      ushort4 o;
      o.x = f2bf(e0); o.y = f2bf(e1); o.z = f2bf(e2); o.w = f2bf(e3);
      *(ushort4*)(P + row * N + colb) = o;
    }
    rs += __shfl_xor(rs, 16);
    rs += __shfl_xor(rs, 32);
    if (lane < 16)
      lp[(bm + wm + mi * 16 + lane) * 64 + cg] = rs;
  }
}

// Batch-combined PV, split-K=2 — NE2R3.
// Grid (8,64) = 512 blocks = exactly 1 round of 2/CU. xcd = b*4+sp*2+mhalf:
// each XCD streams an 8MB probs slice + 4MB vT slice (L2-resident).
__global__ __launch_bounds__(512, 4) void gemm_pv_splitk2(
    const u16* __restrict__ probs, const u16* __restrict__ vT,
    u16* __restrict__ pA, u16* __restrict__ pB)
{
  const int xcd = blockIdx.x;
  const int j = blockIdx.y;                 // [0,64)
  const long b = xcd >> 2;
  const int sp = (xcd >> 1) & 1;
  const int by = (xcd & 1) * 16 + (j & 15); // [0,32)
  const int bx = j >> 4;                    // [0,4)

  NE2_PROLOGUE((long)by * 128, (long)bx * 256);
  const u16* Ab = probs + b * 4096L * 4096 + bm * 4096 + sp * 2048;
  const u16* Bb = vT + b * 1024L * 4096 + bn * 4096 + sp * 2048;
  NE2_SETUP_PTRS(Ab, Bb, 4096);
  u16* part = (b ? pB : pA) + (long)sp * 4096 * 1024;

  NE2_START()
  NE2_LOOP(64, NE2_TILE)

#pragma unroll
  for (int mi = 0; mi < 4; ++mi) {
    long row = bm + wm + mi * 16 + fr;
#pragma unroll
    for (int ni = 0; ni < 4; ++ni) {
      long colb = bn + wn + ni * 16 + oc;
      ushort4 o;
      o.x = f2bf(acc[mi][ni][0]);
      o.y = f2bf(acc[mi][ni][1]);
      o.z = f2bf(acc[mi][ni][2]);
      o.w = f2bf(acc[mi][ni][3]);
      *(ushort4*)(part + row * 1024 + colb) = o;
    }
  }
}

// Fused QKV projection — NE2R3. A=xb [8192,1024], Bt=WqkvT [3072,1024].
// Grid (8,96) = 768 blocks = 1.5 rounds of 2/CU. xcd owns a 1k-row A-band.
// Block-uniform: bx<8 -> q/k (swapped epi); bx>=8 -> v (NS epi into vT).
__global__ __launch_bounds__(512, 4) void gemm_qkv(
    const u16* __restrict__ A, const u16* __restrict__ Bt,
    u16* __restrict__ qb, u16* __restrict__ kb, u16* __restrict__ vT,
    const float* __restrict__ bq, const float* __restrict__ bk,
    const float* __restrict__ bv)
{
  const int xcd = blockIdx.x;
  const int j = blockIdx.y;                 // [0,96)
  const int by = xcd * 8 + (j & 7);         // [0,64)
  const int bx = j >> 3;                    // [0,12)

  NE2_PROLOGUE((long)by * 128, (long)bx * 256);
  const u16* Ab = A + bm * 1024;
  const u16* Bb = Bt + bn * 1024;
  NE2_SETUP_PTRS(Ab, Bb, 1024);

  if (bn < 2048) {
    NE2_START()
    NE2_LOOP(32, NE2_TILE)
    u16* C = (bn < 1024) ? qb : kb;
    const float* bias = (bn < 1024) ? bq : bk;
#pragma unroll
    for (int mi = 0; mi < 4; ++mi) {
      long row = bm + wm + mi * 16 + fr;
#pragma unroll
      for (int ni = 0; ni < 4; ++ni) {
        long colg = bn + wn + ni * 16 + oc;
        long cc = colg & 1023;
        float4 bv4 = *(const float4*)(bias + cc);
        ushort4 o;
        o.x = f2bf(acc[mi][ni][0] + bv4.x);
        o.y = f2bf(acc[mi][ni][1] + bv4.y);
        o.z = f2bf(acc[mi][ni][2] + bv4.z);
        o.w = f2bf(acc[mi][ni][3] + bv4.w);
        *(ushort4*)(C + row * 1024 + cc) = o;
      }
    }
  } else {
    NE2_START()
    NE2_LOOP(32, NE2_TILE_NS)
    const int orow = (lane >> 4) * 4;       // NS: 4 consecutive rows
    const long b_ = bm >> 12;               // block entirely in one batch
    const long s0 = (bm & 4095) + wm;
    u16* vb = vT + b_ * (1024L * 4096);
#pragma unroll
    for (int ni = 0; ni < 4; ++ni) {
      long d = bn + wn + ni * 16 + fr - 2048;
      float bvv = bv[d];
#pragma unroll
      for (int mi = 0; mi < 4; ++mi) {
        long s = s0 + mi * 16 + orow;
        ushort4 o;
        o.x = f2bf(acc[mi][ni][0] + bvv);
        o.y = f2bf(acc[mi][ni][1] + bvv);
        o.z = f2bf(acc[mi][ni][2] + bvv);
        o.w = f2bf(acc[mi][ni][3] + bvv);
        *(ushort4*)(vb + d * 4096L + s) = o;
      }
    }
  }
}

// Final projection — NE2R3. C = ob*WoT^T + bias, fp32 out. Grid (8,32).
__global__ __launch_bounds__(512, 4) void gemm_bt(
    const u16* __restrict__ A, const u16* __restrict__ Bt,
    float* __restrict__ Cout, const float* __restrict__ bias)
{
  const int xcd = blockIdx.x;
  const int j = blockIdx.y;                 // [0,32)
  const int by = xcd * 8 + (j & 7);         // [0,64)
  const int bx = j >> 3;                    // [0,4)

  NE2_PROLOGUE((long)by * 128, (long)bx * 256);
  const u16* Ab = A + bm * 1024;
  const u16* Bb = Bt + bn * 1024;
  NE2_SETUP_PTRS(Ab, Bb, 1024);

  NE2_START()
  NE2_LOOP(32, NE2_TILE)

#pragma unroll
  for (int mi = 0; mi < 4; ++mi) {
    long row = bm + wm + mi * 16 + fr;
#pragma unroll
    for (int ni = 0; ni < 4; ++ni) {
      long colb = bn + wn + ni * 16 + oc;
      float4 bv4 = *(const float4*)(bias + colb);
      float4 o;
      o.x = acc[mi][ni][0] + bv4.x;
      o.y = acc[mi][ni][1] + bv4.y;
      o.z = acc[mi][ni][2] + bv4.z;
      o.w = acc[mi][ni][3] + bv4.w;
      *(float4*)(Cout + row * 1024 + colb) = o;
    }
  }
}

// Combined reduce + softmax-normalize: grid (4096 rows, 2 batches).
__global__ __launch_bounds__(256) void reduce2_div_row(
    const u16* __restrict__ pA, const u16* __restrict__ pB,
    const float* __restrict__ lpartT, u16* __restrict__ ob)
{
  const int row = blockIdx.x;           // [0,4096)
  const long b = blockIdx.y;
  const int tid = threadIdx.x;
  const u16* part = b ? pB : pA;
  const float* lp = lpartT + b * 4096 * 64;
  __shared__ float sl;
  if (tid < 64) {
    float s = lp[(long)row * 64 + tid];
#pragma unroll
    for (int off = 32; off; off >>= 1) s += __shfl_down(s, off);
    if (tid == 0) sl = s;
  }
  __syncthreads();
  const float inv = 1.0f / sl;
  const long base = (long)row * 1024 + tid * 4;
  float acc4[4] = {0.f, 0.f, 0.f, 0.f};
#pragma unroll
  for (int s = 0; s < 2; ++s) {
    ushort4 p = *(const ushort4*)(part + (long)s * 4096 * 1024 + base);
    acc4[0] += bf2f(p.x); acc4[1] += bf2f(p.y);
    acc4[2] += bf2f(p.z); acc4[3] += bf2f(p.w);
  }
  ushort4 o;
  o.x = f2bf(acc4[0] * inv);
  o.y = f2bf(acc4[1] * inv);
  o.z = f2bf(acc4[2] * inv);
  o.w = f2bf(acc4[3] * inv);
  *(ushort4*)(ob + b * 4096L * 1024 + base) = o;
}

// Fused prep: blocks [0,8192) cast x (fp32->bf16, float4); blocks
// [8192,12288) transpose+cast the 4 weight matrices (z = (blk-8192)>>10).
__global__ __launch_bounds__(256) void prep(
    const float* __restrict__ x, u16* __restrict__ xb,
    const float* __restrict__ W0, const float* __restrict__ W1,
    const float* __restrict__ W2, const float* __restrict__ W3,
    u16* __restrict__ O0, u16* __restrict__ O1,
    u16* __restrict__ O2, u16* __restrict__ O3)
{
  __shared__ float tile[32][33];
  int blk = blockIdx.x;
  if (blk < 8192) {
    int i = blk * 256 + threadIdx.x;      // 2M float4s
    float4 f = ((const float4*)x)[i];
    ushort4 o;
    o.x = f2bf(f.x); o.y = f2bf(f.y); o.z = f2bf(f.z); o.w = f2bf(f.w);
    ((ushort4*)xb)[i] = o;
  } else {
    blk -= 8192;
    const int z = blk >> 10, t = blk & 1023;
    const float* in = (z == 0) ? W0 : (z == 1) ? W1 : (z == 2) ? W2 : W3;
    u16* outp = (z == 0) ? O0 : (z == 1) ? O1 : (z == 2) ? O2 : O3;
    const int bx = (t & 31) * 32, by = (t >> 5) * 32;
    const int tx = threadIdx.x & 31, ty = threadIdx.x >> 5;   // 32 x 8
    for (int i = ty; i < 32; i += 8)
      tile[i][tx] = in[(long)(by + i) * 1024 + bx + tx];
    __syncthreads();
    for (int i = ty; i < 32; i += 8)
      outp[(long)(bx + i) * 1024 + by + tx] = f2bf(tile[tx][i]);
  }
}

extern "C" void kernel_launch(void* const* d_in, const int* in_sizes, int n_in,
                              void* d_out, int out_size, void* d_ws, size_t ws_size,
                              hipStream_t stream) {
  const float* x  = (const float*)d_in[0];
  const float* Wq = (const float*)d_in[1];
  const float* bq = (const float*)d_in[2];
  const float* Wk = (const float*)d_in[3];
  const float* bk = (const float*)d_in[4];
  const float* Wv = (const float*)d_in[5];
  const float* bv = (const float*)d_in[6];
  const float* Wo = (const float*)d_in[7];
  const float* bo = (const float*)d_in[8];
  float* out = (float*)d_out;

  const int B = 2, S = 4096, D = 1024;
  const long MB = 1L << 20;

  // ---- workspace layout (top usage 152 MiB; ws_size >= 168 MiB proven) ----
  //  [0,16M)    qb  bf16 [8192,1024]   -- dead after QK_exp; reused as
  //                                       PV bf16 partials batch0 [2][4096][1024]
  //  [16,32M)   kb  bf16 [8192,1024]
  //  [32,48M)   vT  bf16 [B][1024][4096]
  //  [48,64M)   xb  bf16 [8192,1024]   -- aliased with ob (xb dead before PV)
  //  [64,72M)   WqkvT bf16 [3072,1024] + WoT bf16 [1024,1024]
  //  [72,136M)  probs bf16 [B][4096][4096]  (both batches)
  //  [136,152M) PV bf16 partials batch1 [2][4096][1024]
  // d_out (32MB fp32, dead until final proj) hosts lpartT [B][4096][64] fp32.
  char* w = (char*)d_ws;
  u16* qb  = (u16*)(w);
  u16* kb  = (u16*)(w + 16 * MB);
  u16* vT  = (u16*)(w + 32 * MB);
  u16* xb  = (u16*)(w + 48 * MB);
  u16* ob  = xb;                        // alias: xb dead before ob written
  u16* WqkvT = (u16*)(w + 64 * MB);
  u16* WoT = WqkvT + 3072L * 1024;
  u16* probs = (u16*)(w + 72 * MB);
  u16* partA = (u16*)(w);               // over qb, dead after QK_exp
  u16* partB = (u16*)(w + 136 * MB);
  float* lpartT = (float*)d_out;        // [2][4096][64] fp32 = 2MB

  // 1. fused prep: cast x + transpose/cast all 4 weights
  prep<<<dim3(8192 + 4096), 256, 0, stream>>>(
      x, xb, Wq, Wk, Wv, Wo,
      WqkvT, WqkvT + 1024L * 1024, WqkvT + 2048L * 1024, WoT);

  // 2. fused QKV projection: grid (8,96) = 768 blocks (NE2R3, 2/CU)
  gemm_qkv<<<dim3(8, 96), 512, 0, stream>>>(
      xb, WqkvT, qb, kb, vT, bq, bk, bv);

  // 3. attention, both batches per launch (NE2R3, 2/CU)
  const float scale = 0.125f;  // 1/sqrt(64)
  gemm_qk_exp<<<dim3(8, 128), 512, 0, stream>>>(
      qb, kb, probs, lpartT, scale);
  // qb now dead -> partA overlays it
  gemm_pv_splitk2<<<dim3(8, 64), 512, 0, stream>>>(
      probs, vT, partA, partB);
  reduce2_div_row<<<dim3(S, B), 256, 0, stream>>>(partA, partB, lpartT, ob);

  // 4. final projection -> fp32 d_out (NE2R3)
  gemm_bt<<<dim3(8, 32), 512, 0, stream>>>(ob, WoT, out, bo);
}

// Round 7
// 352.293 us; speedup vs baseline: 1.0575x; 1.0309x over previous
//
#include <hip/hip_runtime.h>

// bf16 stored as raw ushort everywhere; MFMA consumes __bf16 vectors.
typedef unsigned short u16;
using bf16x8  = __attribute__((ext_vector_type(8))) __bf16;
using floatx4 = __attribute__((ext_vector_type(4))) float;

__device__ __forceinline__ u16 f2bf(float f) {
  unsigned int u = __builtin_bit_cast(unsigned int, f);
  u += 0x7fffu + ((u >> 16) & 1u);          // round-to-nearest-even
  return (u16)(u >> 16);
}
__device__ __forceinline__ float bf2f(u16 h) {
  unsigned int u = ((unsigned int)h) << 16;
  return __builtin_bit_cast(float, u);
}

#define AS1(p) ((const __attribute__((address_space(1))) void*)(p))
#define AS3(p) ((__attribute__((address_space(3))) void*)(p))
#define SGB()  __builtin_amdgcn_sched_barrier(0)

// ===== NE3: 256x256 phased engine, BK=32, ring-3 (96 KiB), CHUNKED pipe ====
// R6 post-mortem: my lgkmcnt(0)+SGB walls between ds_read block and MFMA
// block forced read/MFMA ALTERNATION (sum, not max). NE3 chunks the 32 MFMA
// into 8x4 and slides one ds_read under each chunk; the COMPILER inserts
// counted lgkmcnt for its own loads (near-optimal per m97 asm), SGB only
// pins the interleave. 256^2 shape: 12 reads / 32 MFMA per wave = best
// LDS:MFMA ratio (1.12). Ring-3 x 32KB slots = 96KB, 1 blk/CU.
// Counted vmcnt: stage(T+2) = 4 loads/thread at tile top; at tile end,
// T+1's 4 must be done, T+2's 4 may fly -> vmcnt(4); T==NT-2 -> vmcnt(0).
// st_16x32 XOR swizzle both-sides (R3-verified, bank-conflict PMC = 0).
#define NE3_PROLOGUE(bmv, bnv)                                               \
  __shared__ u16 lds[49152];            /* 96 KiB = 3 x 32KB slots */        \
  const int tid = threadIdx.x;                                               \
  const int w = tid >> 6, lane = tid & 63;                                   \
  const int wm = (w >> 2) * 128, wn = (w & 3) * 64;                          \
  const int wm16 = (w >> 2) * 8;        /* A subtile base for this wave */   \
  const int wn4  = (w & 3) * 4;         /* B subtile base for this wave */   \
  const long bm = (bmv), bn = (bnv);                                         \
  floatx4 acc[8][4] = {};                                                    \
  const int fr = lane & 15;                                                  \
  const int kq = (lane >> 4) * 8;                                            \
  const int oc = (lane >> 4) * 4;                                            \
  const int swz  = (lane * 16) ^ (((lane >> 5) & 1) << 5);                   \
  const int srow = swz >> 6;                                                 \
  const int scol = (swz & 63) >> 1;                                          \
  const int st0  = w * 2;                                                    \
  const int aoff = fr * 64 + ((kq * 2) ^ (((fr >> 3) & 1) << 5));

#define NE3_SETUP_PTRS(Abp, Bbp, ldK)                                        \
  const u16* A0p = (Abp) + (long)(st0 * 16 + srow) * (ldK) + scol;           \
  const u16* A1p = A0p + 16L * (ldK);                                        \
  const u16* B0p = (Bbp) + (long)(st0 * 16 + srow) * (ldK) + scol;           \
  const u16* B1p = B0p + 16L * (ldK);

// Stage tile TT into ring slot S (slot stride 16384 u16 = 32 KB).
#define NE3_SA(TT, S)                                                        \
  { u16* d_ = lds + (S) * 16384 + st0 * 512;                                 \
    long o_ = (long)(TT) * 32;                                               \
    __builtin_amdgcn_global_load_lds(AS1(A0p + o_), AS3(d_), 16, 0, 0);      \
    __builtin_amdgcn_global_load_lds(AS1(A1p + o_), AS3(d_ + 512), 16, 0, 0); }
#define NE3_SB(TT, S)                                                        \
  { u16* d_ = lds + (S) * 16384 + 8192 + st0 * 512;                          \
    long o_ = (long)(TT) * 32;                                               \
    __builtin_amdgcn_global_load_lds(AS1(B0p + o_), AS3(d_), 16, 0, 0);      \
    __builtin_amdgcn_global_load_lds(AS1(B1p + o_), AS3(d_ + 512), 16, 0, 0); }

// MFMA operand-order variants (c = acc in/out).
#define MFOP_SWAP(b_, a_, c_) __builtin_amdgcn_mfma_f32_16x16x32_bf16((b_), (a_), (c_), 0, 0, 0)
#define MFOP_NS(b_, a_, c_)   __builtin_amdgcn_mfma_f32_16x16x32_bf16((a_), (b_), (c_), 0, 0, 0)

// 4-MFMA chunk: row kk of acc, A-fragment register AREG.
#define NE3_MM(kk, AREG, MFOP)                                               \
    acc[kk][0] = MFOP(bf[0], AREG, acc[kk][0]);                              \
    acc[kk][1] = MFOP(bf[1], AREG, acc[kk][1]);                              \
    acc[kk][2] = MFOP(bf[2], AREG, acc[kk][2]);                              \
    acc[kk][3] = MFOP(bf[3], AREG, acc[kk][3]);

// One K-tile: stage(T+2)->sW, then software-pipelined 8 chunks of
// {1 ds_read || 4 MFMA}. No manual lgkmcnt — compiler inserts counted waits.
#define NE3_TILE_G(T, NT, sR, sW, MFOP)                                      \
  {                                                                          \
    const char* sb_ = (const char*)lds + (sR) * 32768;                       \
    if ((T) + 2 < (NT)) { NE3_SB((T) + 2, sW) NE3_SA((T) + 2, sW) }          \
    bf16x8 bf[4], afA, afB, afC;                                             \
    bf[0] = *(const bf16x8*)(sb_ + 16384 + (wn4 + 0) * 1024 + aoff);         \
    bf[1] = *(const bf16x8*)(sb_ + 16384 + (wn4 + 1) * 1024 + aoff);         \
    bf[2] = *(const bf16x8*)(sb_ + 16384 + (wn4 + 2) * 1024 + aoff);         \
    bf[3] = *(const bf16x8*)(sb_ + 16384 + (wn4 + 3) * 1024 + aoff);         \
    afA = *(const bf16x8*)(sb_ + (wm16 + 0) * 1024 + aoff);                  \
    afB = *(const bf16x8*)(sb_ + (wm16 + 1) * 1024 + aoff);                  \
    SGB();                                                                   \
    __builtin_amdgcn_s_setprio(1);                                           \
    afC = *(const bf16x8*)(sb_ + (wm16 + 2) * 1024 + aoff);                  \
    SGB(); NE3_MM(0, afA, MFOP) SGB();                                       \
    afA = *(const bf16x8*)(sb_ + (wm16 + 3) * 1024 + aoff);                  \
    SGB(); NE3_MM(1, afB, MFOP) SGB();                                       \
    afB = *(const bf16x8*)(sb_ + (wm16 + 4) * 1024 + aoff);                  \
    SGB(); NE3_MM(2, afC, MFOP) SGB();                                       \
    afC = *(const bf16x8*)(sb_ + (wm16 + 5) * 1024 + aoff);                  \
    SGB(); NE3_MM(3, afA, MFOP) SGB();                                       \
    afA = *(const bf16x8*)(sb_ + (wm16 + 6) * 1024 + aoff);                  \
    SGB(); NE3_MM(4, afB, MFOP) SGB();                                       \
    afB = *(const bf16x8*)(sb_ + (wm16 + 7) * 1024 + aoff);                  \
    SGB(); NE3_MM(5, afC, MFOP) SGB();                                       \
    NE3_MM(6, afA, MFOP) SGB();                                              \
    NE3_MM(7, afB, MFOP)                                                     \
    __builtin_amdgcn_s_setprio(0);                                           \
    if ((T) < (NT) - 2)       { asm volatile("s_waitcnt vmcnt(4)" ::: "memory"); } \
    else if ((T) == (NT) - 2) { asm volatile("s_waitcnt vmcnt(0)" ::: "memory"); } \
    __builtin_amdgcn_s_barrier();                                            \
    SGB();                                                                   \
  }

#define NE3_START()                                                          \
  NE3_SA(0, 0) NE3_SB(0, 0) NE3_SA(1, 1) NE3_SB(1, 1)                        \
  asm volatile("s_waitcnt vmcnt(4)" ::: "memory");                           \
  __builtin_amdgcn_s_barrier();                                              \
  SGB();

#define NE3_LOOP(NT, MFOP)                                                   \
  {                                                                          \
    int sR = 0, sW = 2;                                                      \
    for (int T = 0; T < (NT); ++T) {                                         \
      NE3_TILE_G(T, (NT), sR, sW, MFOP)                                      \
      sR = (sR == 2) ? 0 : sR + 1;                                           \
      sW = (sW == 2) ? 0 : sW + 1;                                           \
    }                                                                        \
  }

// ======= NE2R3: 128x256 ring-3 engine (R6-verified) — kept for bt =========
#define NE2_PROLOGUE(bmv, bnv)                                               \
  __shared__ u16 lds[36864];            /* 72 KiB = 3 x 24KB */              \
  const int tid = threadIdx.x;                                               \
  const int w = tid >> 6, lane = tid & 63;                                   \
  const int wm = (w >> 2) * 64, wn = (w & 3) * 64;                           \
  const int wm4 = (w >> 2) * 4;                                              \
  const int wn4 = (w & 3) * 4;                                               \
  const long bm = (bmv), bn = (bnv);                                         \
  floatx4 acc[4][4] = {};                                                    \
  const int fr = lane & 15;                                                  \
  const int kq = (lane >> 4) * 8;                                            \
  const int oc = (lane >> 4) * 4;                                            \
  const int swz  = (lane * 16) ^ (((lane >> 5) & 1) << 5);                   \
  const int srow = swz >> 6;                                                 \
  const int scol = (swz & 63) >> 1;                                          \
  const int st0  = w * 2;                                                    \
  const int aoff = fr * 64 + ((kq * 2) ^ (((fr >> 3) & 1) << 5));

#define NE2_SETUP_PTRS(Abp, Bbp, ldK)                                        \
  const u16* A0p = (Abp) + (long)(w * 16 + srow) * (ldK) + scol;             \
  const u16* B0p = (Bbp) + (long)(st0 * 16 + srow) * (ldK) + scol;           \
  const u16* B1p = B0p + 16L * (ldK);

#define NE2_SA(TT, S)                                                        \
  { u16* d_ = lds + (S) * 12288 + w * 512;                                   \
    __builtin_amdgcn_global_load_lds(AS1(A0p + (long)(TT) * 32), AS3(d_), 16, 0, 0); }
#define NE2_SB(TT, S)                                                        \
  { u16* d_ = lds + (S) * 12288 + 4096 + st0 * 512;                          \
    long o_ = (long)(TT) * 32;                                               \
    __builtin_amdgcn_global_load_lds(AS1(B0p + o_), AS3(d_), 16, 0, 0);      \
    __builtin_amdgcn_global_load_lds(AS1(B1p + o_), AS3(d_ + 512), 16, 0, 0); }

#define NE_MF_SWAP(mi, ni, c) __builtin_amdgcn_mfma_f32_16x16x32_bf16(bf[ni], af[mi], (c), 0, 0, 0)

#define NE2_TILE_G(T, NT, sR, sW, MF)                                        \
  {                                                                          \
    const char* sb_ = (const char*)lds + (sR) * 24576;                       \
    if ((T) + 2 < (NT)) { NE2_SB((T) + 2, sW) NE2_SA((T) + 2, sW) }          \
    bf16x8 af[4], bf[4];                                                     \
    _Pragma("unroll")                                                        \
    for (int i = 0; i < 4; ++i)                                              \
      af[i] = *(const bf16x8*)(sb_ + (wm4 + i) * 1024 + aoff);               \
    _Pragma("unroll")                                                        \
    for (int i = 0; i < 4; ++i)                                              \
      bf[i] = *(const bf16x8*)(sb_ + 8192 + (wn4 + i) * 1024 + aoff);        \
    asm volatile("s_waitcnt lgkmcnt(0)" ::: "memory");                       \
    SGB();                                                                   \
    __builtin_amdgcn_s_setprio(1);                                           \
    _Pragma("unroll")                                                        \
    for (int mi = 0; mi < 4; ++mi)                                           \
      _Pragma("unroll")                                                      \
      for (int ni = 0; ni < 4; ++ni)                                         \
        acc[mi][ni] = MF(mi, ni, acc[mi][ni]);                               \
    __builtin_amdgcn_s_setprio(0);                                           \
    if ((T) < (NT) - 2)       { asm volatile("s_waitcnt vmcnt(3)" ::: "memory"); } \
    else if ((T) == (NT) - 2) { asm volatile("s_waitcnt vmcnt(0)" ::: "memory"); } \
    __builtin_amdgcn_s_barrier();                                            \
    SGB();                                                                   \
  }

#define NE2_START()                                                          \
  NE2_SA(0, 0) NE2_SB(0, 0) NE2_SA(1, 1) NE2_SB(1, 1)                        \
  asm volatile("s_waitcnt vmcnt(3)" ::: "memory");                           \
  __builtin_amdgcn_s_barrier();                                              \
  SGB();

#define NE2_LOOP(NT, TILE_MACRO)                                             \
  {                                                                          \
    int sR = 0, sW = 2;                                                      \
    for (int T = 0; T < (NT); ++T) {                                         \
      TILE_MACRO(T, (NT), sR, sW)                                            \
      sR = (sR == 2) ? 0 : sR + 1;                                           \
      sW = (sW == 2) ? 0 : sW + 1;                                           \
    }                                                                        \
  }

#define NE2_TILE(T, NT, sR, sW) NE2_TILE_G(T, NT, sR, sW, NE_MF_SWAP)

// Batch-combined QK^T + unnormalized exp — NE3 chunked 256^2 engine.
// Grid (8,64) = 512 blocks x 512 thr. xcd owns a 4-row by-band of batch
// xcd>>2. P = exp(scale*q k^T) bf16; lpartT[b][row][64] fp32.
__global__ __launch_bounds__(512, 2) void gemm_qk_exp(
    const u16* __restrict__ q, const u16* __restrict__ k,
    u16* __restrict__ probs, float* __restrict__ lpartT, float alpha)
{
  const int N = 4096;
  const int xcd = blockIdx.x;
  const int j = blockIdx.y;
  const long b = xcd >> 2;
  const int by = (xcd & 3) * 4 + (j & 3);   // [0,16)
  const int bx = j >> 2;                    // [0,16)

  NE3_PROLOGUE((long)by * 256, (long)bx * 256);
  const u16* Ab = q + b * 4096 * 1024 + bm * 1024;
  const u16* Bb = k + b * 4096 * 1024 + bn * 1024;
  NE3_SETUP_PTRS(Ab, Bb, 1024);
  u16* P = probs + b * 4096L * 4096;
  float* lp = lpartT + b * 4096 * 64;

  NE3_START()
  NE3_LOOP(32, MFOP_SWAP)

  const float a2 = alpha * 1.44269504f;     // exp(x*alpha) = exp2(x*a2)
  const int cg = bx * 4 + (w & 3);          // 64-col group index
#pragma unroll
  for (int mi = 0; mi < 8; ++mi) {
    long row = bm + wm + mi * 16 + fr;
    float rs = 0.f;
#pragma unroll
    for (int ni = 0; ni < 4; ++ni) {
      long colb = bn + wn + ni * 16 + oc;
      float e0 = __builtin_amdgcn_exp2f(acc[mi][ni][0] * a2);
      float e1 = __builtin_amdgcn_exp2f(acc[mi][ni][1] * a2);
      float e2 = __builtin_amdgcn_exp2f(acc[mi][ni][2] * a2);
      float e3 = __builtin_amdgcn_exp2f(acc[mi][ni][3] * a2);
      rs += (e0 + e1) + (e2 + e3);
      ushort4 o;
      o.x = f2bf(e0); o.y = f2bf(e1); o.z = f2bf(e2); o.w = f2bf(e3);
      *(ushort4*)(P + row * N + colb) = o;
    }
    rs += __shfl_xor(rs, 16);
    rs += __shfl_xor(rs, 32);
    if (lane < 16)
      lp[(bm + wm + mi * 16 + lane) * 64 + cg] = rs;
  }
}

// Batch-combined PV, split-K=2 — NE3 chunked 256^2 engine.
// Grid (8,32) = 256 blocks = 1 round of 1/CU. xcd = b*4 + sp*2 + mhalf.
__global__ __launch_bounds__(512, 2) void gemm_pv_splitk2(
    const u16* __restrict__ probs, const u16* __restrict__ vT,
    u16* __restrict__ pA, u16* __restrict__ pB)
{
  const int xcd = blockIdx.x;
  const int j = blockIdx.y;
  const long b = xcd >> 2;
  const int sp = (xcd >> 1) & 1;
  const int by = (xcd & 1) * 8 + (j & 7);   // [0,16)
  const int bx = j >> 3;                    // [0,4)

  NE3_PROLOGUE((long)by * 256, (long)bx * 256);
  const u16* Ab = probs + b * 4096L * 4096 + bm * 4096 + sp * 2048;
  const u16* Bb = vT + b * 1024L * 4096 + bn * 4096 + sp * 2048;
  NE3_SETUP_PTRS(Ab, Bb, 4096);
  u16* part = (b ? pB : pA) + (long)sp * 4096 * 1024;

  NE3_START()
  NE3_LOOP(64, MFOP_SWAP)

#pragma unroll
  for (int mi = 0; mi < 8; ++mi) {
    long row = bm + wm + mi * 16 + fr;
#pragma unroll
    for (int ni = 0; ni < 4; ++ni) {
      long colb = bn + wn + ni * 16 + oc;
      ushort4 o;
      o.x = f2bf(acc[mi][ni][0]);
      o.y = f2bf(acc[mi][ni][1]);
      o.z = f2bf(acc[mi][ni][2]);
      o.w = f2bf(acc[mi][ni][3]);
      *(ushort4*)(part + row * 1024 + colb) = o;
    }
  }
}

// Fused QKV projection — NE3 chunked 256^2 engine. Grid (8,48) = 384 blocks.
// xcd owns a 1k-row A-band. bx<8 -> q/k (swapped epi); bx>=8 -> v (NS epi).
__global__ __launch_bounds__(512, 2) void gemm_qkv(
    const u16* __restrict__ A, const u16* __restrict__ Bt,
    u16* __restrict__ qb, u16* __restrict__ kb, u16* __restrict__ vT,
    const float* __restrict__ bq, const float* __restrict__ bk,
    const float* __restrict__ bv)
{
  const int xcd = blockIdx.x;
  const int j = blockIdx.y;                 // [0,48)
  const int by = xcd * 4 + (j & 3);         // [0,32)
  const int bx = j >> 2;                    // [0,12)

  NE3_PROLOGUE((long)by * 256, (long)bx * 256);
  const u16* Ab = A + bm * 1024;
  const u16* Bb = Bt + bn * 1024;
  NE3_SETUP_PTRS(Ab, Bb, 1024);

  if (bn < 2048) {
    NE3_START()
    NE3_LOOP(32, MFOP_SWAP)
    u16* C = (bn < 1024) ? qb : kb;
    const float* bias = (bn < 1024) ? bq : bk;
#pragma unroll
    for (int mi = 0; mi < 8; ++mi) {
      long row = bm + wm + mi * 16 + fr;
#pragma unroll
      for (int ni = 0; ni < 4; ++ni) {
        long colg = bn + wn + ni * 16 + oc;
        long cc = colg & 1023;
        float4 bv4 = *(const float4*)(bias + cc);
        ushort4 o;
        o.x = f2bf(acc[mi][ni][0] + bv4.x);
        o.y = f2bf(acc[mi][ni][1] + bv4.y);
        o.z = f2bf(acc[mi][ni][2] + bv4.z);
        o.w = f2bf(acc[mi][ni][3] + bv4.w);
        *(ushort4*)(C + row * 1024 + cc) = o;
      }
    }
  } else {
    NE3_START()
    NE3_LOOP(32, MFOP_NS)
    const int orow = (lane >> 4) * 4;       // NS: 4 consecutive rows
    const long b_ = bm >> 12;               // block entirely in one batch
    const long s0 = (bm & 4095) + wm;
    u16* vb = vT + b_ * (1024L * 4096);
#pragma unroll
    for (int ni = 0; ni < 4; ++ni) {
      long d = bn + wn + ni * 16 + fr - 2048;
      float bvv = bv[d];
#pragma unroll
      for (int mi = 0; mi < 8; ++mi) {
        long s = s0 + mi * 16 + orow;
        ushort4 o;
        o.x = f2bf(acc[mi][ni][0] + bvv);
        o.y = f2bf(acc[mi][ni][1] + bvv);
        o.z = f2bf(acc[mi][ni][2] + bvv);
        o.w = f2bf(acc[mi][ni][3] + bvv);
        *(ushort4*)(vb + d * 4096L + s) = o;
      }
    }
  }
}

// Final projection — NE2R3 (R6-verified). C = ob*WoT^T + bias, fp32 out.
__global__ __launch_bounds__(512, 4) void gemm_bt(
    const u16* __restrict__ A, const u16* __restrict__ Bt,
    float* __restrict__ Cout, const float* __restrict__ bias)
{
  const int xcd = blockIdx.x;
  const int j = blockIdx.y;                 // [0,32)
  const int by = xcd * 8 + (j & 7);         // [0,64)
  const int bx = j >> 3;                    // [0,4)

  NE2_PROLOGUE((long)by * 128, (long)bx * 256);
  const u16* Ab = A + bm * 1024;
  const u16* Bb = Bt + bn * 1024;
  NE2_SETUP_PTRS(Ab, Bb, 1024);

  NE2_START()
  NE2_LOOP(32, NE2_TILE)

#pragma unroll
  for (int mi = 0; mi < 4; ++mi) {
    long row = bm + wm + mi * 16 + fr;
#pragma unroll
    for (int ni = 0; ni < 4; ++ni) {
      long colb = bn + wn + ni * 16 + oc;
      float4 bv4 = *(const float4*)(bias + colb);
      float4 o;
      o.x = acc[mi][ni][0] + bv4.x;
      o.y = acc[mi][ni][1] + bv4.y;
      o.z = acc[mi][ni][2] + bv4.z;
      o.w = acc[mi][ni][3] + bv4.w;
      *(float4*)(Cout + row * 1024 + colb) = o;
    }
  }
}

// Combined reduce + softmax-normalize: grid (4096 rows, 2 batches).
__global__ __launch_bounds__(256) void reduce2_div_row(
    const u16* __restrict__ pA, const u16* __restrict__ pB,
    const float* __restrict__ lpartT, u16* __restrict__ ob)
{
  const int row = blockIdx.x;           // [0,4096)
  const long b = blockIdx.y;
  const int tid = threadIdx.x;
  const u16* part = b ? pB : pA;
  const float* lp = lpartT + b * 4096 * 64;
  __shared__ float sl;
  if (tid < 64) {
    float s = lp[(long)row * 64 + tid];
#pragma unroll
    for (int off = 32; off; off >>= 1) s += __shfl_down(s, off);
    if (tid == 0) sl = s;
  }
  __syncthreads();
  const float inv = 1.0f / sl;
  const long base = (long)row * 1024 + tid * 4;
  float acc4[4] = {0.f, 0.f, 0.f, 0.f};
#pragma unroll
  for (int s = 0; s < 2; ++s) {
    ushort4 p = *(const ushort4*)(part + (long)s * 4096 * 1024 + base);
    acc4[0] += bf2f(p.x); acc4[1] += bf2f(p.y);
    acc4[2] += bf2f(p.z); acc4[3] += bf2f(p.w);
  }
  ushort4 o;
  o.x = f2bf(acc4[0] * inv);
  o.y = f2bf(acc4[1] * inv);
  o.z = f2bf(acc4[2] * inv);
  o.w = f2bf(acc4[3] * inv);
  *(ushort4*)(ob + b * 4096L * 1024 + base) = o;
}

// Fused prep: blocks [0,8192) cast x (fp32->bf16, float4); blocks
// [8192,12288) transpose+cast the 4 weight matrices (z = (blk-8192)>>10).
__global__ __launch_bounds__(256) void prep(
    const float* __restrict__ x, u16* __restrict__ xb,
    const float* __restrict__ W0, const float* __restrict__ W1,
    const float* __restrict__ W2, const float* __restrict__ W3,
    u16* __restrict__ O0, u16* __restrict__ O1,
    u16* __restrict__ O2, u16* __restrict__ O3)
{
  __shared__ float tile[32][33];
  int blk = blockIdx.x;
  if (blk < 8192) {
    int i = blk * 256 + threadIdx.x;      // 2M float4s
    float4 f = ((const float4*)x)[i];
    ushort4 o;
    o.x = f2bf(f.x); o.y = f2bf(f.y); o.z = f2bf(f.z); o.w = f2bf(f.w);
    ((ushort4*)xb)[i] = o;
  } else {
    blk -= 8192;
    const int z = blk >> 10, t = blk & 1023;
    const float* in = (z == 0) ? W0 : (z == 1) ? W1 : (z == 2) ? W2 : W3;
    u16* outp = (z == 0) ? O0 : (z == 1) ? O1 : (z == 2) ? O2 : O3;
    const int bx = (t & 31) * 32, by = (t >> 5) * 32;
    const int tx = threadIdx.x & 31, ty = threadIdx.x >> 5;   // 32 x 8
    for (int i = ty; i < 32; i += 8)
      tile[i][tx] = in[(long)(by + i) * 1024 + bx + tx];
    __syncthreads();
    for (int i = ty; i < 32; i += 8)
      outp[(long)(bx + i) * 1024 + by + tx] = f2bf(tile[tx][i]);
  }
}

extern "C" void kernel_launch(void* const* d_in, const int* in_sizes, int n_in,
                              void* d_out, int out_size, void* d_ws, size_t ws_size,
                              hipStream_t stream) {
  const float* x  = (const float*)d_in[0];
  const float* Wq = (const float*)d_in[1];
  const float* bq = (const float*)d_in[2];
  const float* Wk = (const float*)d_in[3];
  const float* bk = (const float*)d_in[4];
  const float* Wv = (const float*)d_in[5];
  const float* bv = (const float*)d_in[6];
  const float* Wo = (const float*)d_in[7];
  const float* bo = (const float*)d_in[8];
  float* out = (float*)d_out;

  const int B = 2, S = 4096, D = 1024;
  const long MB = 1L << 20;

  // ---- workspace layout (top usage 152 MiB; ws_size >= 168 MiB proven) ----
  //  [0,16M)    qb  bf16 [8192,1024]   -- dead after QK_exp; reused as
  //                                       PV bf16 partials batch0 [2][4096][1024]
  //  [16,32M)   kb  bf16 [8192,1024]
  //  [32,48M)   vT  bf16 [B][1024][4096]
  //  [48,64M)   xb  bf16 [8192,1024]   -- aliased with ob (xb dead before PV)
  //  [64,72M)   WqkvT bf16 [3072,1024] + WoT bf16 [1024,1024]
  //  [72,136M)  probs bf16 [B][4096][4096]  (both batches)
  //  [136,152M) PV bf16 partials batch1 [2][4096][1024]
  // d_out (32MB fp32, dead until final proj) hosts lpartT [B][4096][64] fp32.
  char* w = (char*)d_ws;
  u16* qb  = (u16*)(w);
  u16* kb  = (u16*)(w + 16 * MB);
  u16* vT  = (u16*)(w + 32 * MB);
  u16* xb  = (u16*)(w + 48 * MB);
  u16* ob  = xb;                        // alias: xb dead before ob written
  u16* WqkvT = (u16*)(w + 64 * MB);
  u16* WoT = WqkvT + 3072L * 1024;
  u16* probs = (u16*)(w + 72 * MB);
  u16* partA = (u16*)(w);               // over qb, dead after QK_exp
  u16* partB = (u16*)(w + 136 * MB);
  float* lpartT = (float*)d_out;        // [2][4096][64] fp32 = 2MB

  // 1. fused prep: cast x + transpose/cast all 4 weights
  prep<<<dim3(8192 + 4096), 256, 0, stream>>>(
      x, xb, Wq, Wk, Wv, Wo,
      WqkvT, WqkvT + 1024L * 1024, WqkvT + 2048L * 1024, WoT);

  // 2. fused QKV projection: grid (8,48) = 384 blocks (NE3)
  gemm_qkv<<<dim3(8, 48), 512, 0, stream>>>(
      xb, WqkvT, qb, kb, vT, bq, bk, bv);

  // 3. attention, both batches per launch (NE3)
  const float scale = 0.125f;  // 1/sqrt(64)
  gemm_qk_exp<<<dim3(8, 64), 512, 0, stream>>>(
      qb, kb, probs, lpartT, scale);
  // qb now dead -> partA overlays it
  gemm_pv_splitk2<<<dim3(8, 32), 512, 0, stream>>>(
      probs, vT, partA, partB);
  reduce2_div_row<<<dim3(S, B), 256, 0, stream>>>(partA, partB, lpartT, ob);

  // 4. final projection -> fp32 d_out (NE2R3)
  gemm_bt<<<dim3(8, 32), 512, 0, stream>>>(ob, WoT, out, bo);
}